// Round 1
// baseline (415.478 us; speedup 1.0000x reference)
//
#include <hip/hip_runtime.h>

typedef __attribute__((ext_vector_type(8))) __bf16 bf16x8;
typedef __attribute__((ext_vector_type(4))) __bf16 bf16x4;
typedef __attribute__((ext_vector_type(4))) float f32x4;
typedef __attribute__((ext_vector_type(4))) short s16x4;
typedef __attribute__((ext_vector_type(8))) short s16x8;

#define MFMA32(a,b,c) __builtin_amdgcn_mfma_f32_16x16x32_bf16(a, b, c, 0, 0, 0)

static __device__ inline f32x4 MFMAX16(s16x4 a, s16x4 b, f32x4 c) {
#if __has_builtin(__builtin_amdgcn_mfma_f32_16x16x16bf16_1k)
  return __builtin_amdgcn_mfma_f32_16x16x16bf16_1k(a, b, c, 0, 0, 0);
#else
  f32x4 d;
  asm("v_mfma_f32_16x16x16_bf16 %0, %1, %2, %3" : "=v"(d) : "v"(a), "v"(b), "v"(c));
  return d;
#endif
}

#define KS 40    // k_s row stride (elems); row=token, d interleaved as quad*8+nt*4 (16B-aligned b128 frags)
#define VS 212   // vT_s row stride (elems)
#define NW 4     // waves per block
#define LOG2E 1.4426950408889634f

__device__ inline void lnrelu8(float* v, const float* g, const float* bta) {
  float mu = 0.f;
#pragma unroll
  for (int i = 0; i < 8; i++) mu += v[i];
  mu *= 0.125f;
  float var = 0.f;
#pragma unroll
  for (int i = 0; i < 8; i++) { float d = v[i] - mu; var += d * d; }
  var *= 0.125f;
  float inv = rsqrtf(var + 1e-5f);
#pragma unroll
  for (int i = 0; i < 8; i++) v[i] = fmaxf((v[i] - mu) * inv * g[i] + bta[i], 0.f);
}

// ---- merged prep: blocks 0..87 weight repack; blocks 88..256 pos-MLP + bias table
// biasP layout: [h][qi][quad][kt*4+r]  (52 elems = 104B contiguous per (qi,quad) lane-row,
// so k_attn loads its 13 kt chunks as dense dwordx2 with immediate offsets off ONE base).
// Values pre-multiplied by log2e so k_attn can use raw v_exp_f32 (exp2).
__global__ void k_prep(const float* __restrict__ wq, const float* __restrict__ wkv,
                       const float* __restrict__ wproj,
                       const float* __restrict__ pp_w, const float* __restrict__ pp_b,
                       const float* ln1_g, const float* ln1_b, const float* l1_w, const float* l1_b,
                       const float* ln2_g, const float* ln2_b, const float* l2_w, const float* l2_b,
                       const float* ln3_g, const float* ln3_b, const float* l3_w, const float* l3_b,
                       __bf16* __restrict__ wF, __bf16* __restrict__ wpT,
                       __bf16* __restrict__ biasP) {
  __shared__ float pos_s[4 * 729];
  int blk = blockIdx.x, tid = threadIdx.x;
  if (blk < 88) {
    int t = blk * 256 + tid;
    if (t < 6144) {          // 96 frags x 64 lanes; frag = ((h*3+tt)*2+nt)*4+kc
      int lane = t & 63, frag = t >> 6;
      int kc = frag & 3, nt = (frag >> 2) & 1, tt = (frag >> 3) % 3, h = frag / 24;
      int col = lane & 15, quad = lane >> 4;
      int o = h * 32 + nt * 16 + col;
      int ibase = kc * 32 + quad * 8;
      bf16x8 vv;
#pragma unroll
      for (int j = 0; j < 8; j++) {
        int in = ibase + j;
        float w = (tt == 0) ? wq[in * 128 + o]
                : (tt == 1) ? wkv[in * 256 + o]
                            : wkv[in * 256 + 128 + o];
        vv[j] = (__bf16)w;
      }
      *(bf16x8*)&wF[(size_t)t * 8] = vv;
    } else if (t < 6144 + 16384) {
      int t2 = t - 6144;
      int o = t2 >> 7, i = t2 & 127;
      wpT[t2] = (__bf16)wproj[i * 128 + o];
    }
    return;
  }
  // bias blocks: recompute the tiny pos MLP into LDS, then emit bias slice
  for (int m = tid; m < 729; m += 256) {
    float dr = (float)(m / 27) - 13.f, dc = (float)(m % 27) - 13.f;
    float a[8], bv[8];
#pragma unroll
    for (int j = 0; j < 8; j++) a[j] = dr * pp_w[j] + dc * pp_w[8 + j] + pp_b[j];
    lnrelu8(a, ln1_g, ln1_b);
#pragma unroll
    for (int o = 0; o < 8; o++) {
      float s = l1_b[o];
#pragma unroll
      for (int j = 0; j < 8; j++) s += a[j] * l1_w[j * 8 + o];
      bv[o] = s;
    }
    lnrelu8(bv, ln2_g, ln2_b);
#pragma unroll
    for (int o = 0; o < 8; o++) {
      float s = l2_b[o];
#pragma unroll
      for (int j = 0; j < 8; j++) s += bv[j] * l2_w[j * 8 + o];
      a[o] = s;
    }
    lnrelu8(a, ln3_g, ln3_b);
#pragma unroll
    for (int o = 0; o < 4; o++) {
      float s = l3_b[o];
#pragma unroll
      for (int j = 0; j < 8; j++) s += a[j] * l3_w[j * 4 + o];
      pos_s[o * 729 + m] = s;
    }
  }
  __syncthreads();
  int t = (blk - 88) * 256 + tid;           // 169*256 == 4*208*52 exactly
  int g = t % 52; int rem = t / 52; int qi = rem % 208; int h = rem / 208;
  int kt = g >> 2, qd = g & 3;              // kj = kt*16 + qd*4 + r
  int kj0 = g * 4;
  int r1 = qi / 14, c1 = qi % 14;
  bf16x4 o;
#pragma unroll
  for (int r = 0; r < 4; r++) {
    int kj = kj0 + r;
    float v = 0.f;
    if (qi < 196 && kj < 196) {
      int r2 = kj / 14, c2 = kj % 14;
      v = pos_s[h * 729 + (r1 - r2 + 13) * 27 + (c1 - c2 + 13)];
    }
    o[r] = (__bf16)(v * LOG2E);
  }
  *(bf16x4*)&biasP[(((size_t)h * 208 + qi) * 4 + qd) * 52 + kt * 4] = o;
}

// ---------------- fused attention: one block (4 waves) per (b,h) -------------
// Restructured q-phase pipeline: S and PV merged per kt (no pp[13] array),
// bias rows for the NEXT tile refilled inside the kt loop right after use,
// first tile's bias loaded before the barrier, stage-B x double-buffered.
__launch_bounds__(256, 4)
__global__ void k_attn(const float* __restrict__ x, const __bf16* __restrict__ wF,
                       const __bf16* __restrict__ biasP, __bf16* __restrict__ Og) {
  __shared__ __align__(16) __bf16 k_s[208 * KS];    // 16640 B [token][d interleaved]
  __shared__ __align__(16) __bf16 vT_s[32 * VS];    // 13568 B [d][token]

  int tid = threadIdx.x;
  int wv = tid >> 6, lane = tid & 63, col = lane & 15, quad = lane >> 4;
  int bi = blockIdx.x;
  int b = (bi & 7) * 128 + (bi >> 5);   // same-b heads -> same XCD
  int h = (bi >> 3) & 3;

  const __bf16* wH = wF + (size_t)h * 12288;
#define WG(t, nt, kc) (*(const bf16x8*)&wH[(((t) * 2 + (nt)) * 4 + (kc)) * 512 + lane * 8])

  const float* xb = x + (size_t)b * (196 * 128);
  const float scale = 0.17677669529663687f * LOG2E;   // 32^-0.5, exp2-folded

  s16x4 qb[4][2];   // persisted q B-frags for this wave's tiles
  float4 xr[8];     // raw-x double-buffer (one tile in flight)

  // preload x for first owned tile
  {
    int row0 = wv * 16 + col;
    const float4* q4 = (const float4*)(xb + (size_t)(row0 < 196 ? row0 : 0) * 128 + quad * 8);
#pragma unroll
    for (int kc = 0; kc < 4; kc++) { xr[2 * kc] = q4[kc * 8]; xr[2 * kc + 1] = q4[kc * 8 + 1]; }
  }

  // ---- Stage B: per owned tile, convert x; prefetch next tile's x; k,v -> LDS, q -> regs
#pragma unroll
  for (int i = 0; i < 4; i++) {
    int qt = wv + i * NW;
    if (qt < 13) {
      bf16x8 xf[4];
#pragma unroll
      for (int kc = 0; kc < 4; kc++) {
        float4 u = xr[2 * kc], v = xr[2 * kc + 1];
        bf16x8 r;
        r[0] = (__bf16)u.x; r[1] = (__bf16)u.y; r[2] = (__bf16)u.z; r[3] = (__bf16)u.w;
        r[4] = (__bf16)v.x; r[5] = (__bf16)v.y; r[6] = (__bf16)v.z; r[7] = (__bf16)v.w;
        xf[kc] = r;
      }
      int qn = qt + NW;
      if (i < 3 && qn < 13) {           // issue next tile's x loads under this tile's MFMAs
        int row = qn * 16 + col;
        const float4* q4 = (const float4*)(xb + (size_t)(row < 196 ? row : 0) * 128 + quad * 8);
#pragma unroll
        for (int kc = 0; kc < 4; kc++) { xr[2 * kc] = q4[kc * 8]; xr[2 * kc + 1] = q4[kc * 8 + 1]; }
      }
      int row = qt * 16 + col;
#pragma unroll
      for (int nt = 0; nt < 2; nt++) {       // k, swapped: D[od][token] -> interleaved layout
        f32x4 acc = {0.f, 0.f, 0.f, 0.f};
#pragma unroll
        for (int kc = 0; kc < 4; kc++) acc = MFMA32(WG(1, nt, kc), xf[kc], acc);
        bf16x4 pk;
#pragma unroll
        for (int r = 0; r < 4; r++) pk[r] = (__bf16)acc[r];
        *(bf16x4*)&k_s[row * KS + quad * 8 + nt * 4] = pk;
      }
#pragma unroll
      for (int nt = 0; nt < 2; nt++) {       // v, normal: D[token][od] -> vT_s[od][token]
        f32x4 acc = {0.f, 0.f, 0.f, 0.f};
#pragma unroll
        for (int kc = 0; kc < 4; kc++) acc = MFMA32(xf[kc], WG(2, nt, kc), acc);
        bf16x4 pk;
#pragma unroll
        for (int r = 0; r < 4; r++) pk[r] = (__bf16)acc[r];
        *(bf16x4*)&vT_s[(nt * 16 + col) * VS + qt * 16 + quad * 4] = pk;
      }
#pragma unroll
      for (int nt = 0; nt < 2; nt++) {       // q, swapped -> registers (scale exp2-folded)
        f32x4 acc = {0.f, 0.f, 0.f, 0.f};
#pragma unroll
        for (int kc = 0; kc < 4; kc++) acc = MFMA32(WG(0, nt, kc), xf[kc], acc);
        bf16x4 pk;
#pragma unroll
        for (int r = 0; r < 4; r++) pk[r] = (__bf16)(acc[r] * scale);
        qb[i][nt] = __builtin_bit_cast(s16x4, pk);
      }
    }
  }

  // first tile's bias rows: 13 dense dwordx2 off one base, complete by barrier drain
  bf16x4 bl[13];
  {
    int qi0 = wv * 16 + col;
    const __bf16* bp = biasP + (((size_t)h * 208 + qi0) * 4 + quad) * 52;
#pragma unroll
    for (int kt = 0; kt < 13; kt++) bl[kt] = *(const bf16x4*)(bp + kt * 4);
  }
  __syncthreads();

  // ---- q-phase: merged S -> exp2 -> PV per kt; next tile's bias refilled in-loop
#pragma unroll
  for (int i = 0; i < 4; i++) {
    int qt = wv + i * NW;
    if (qt < 13) {
      int qi = qt * 16 + col;
      int qn = qt + NW;
      bool nxt = (i < 3) && (qn < 13);
      const __bf16* bpn = biasP + (((size_t)h * 208 + (qn * 16 + col)) * 4 + quad) * 52;

      float sum = 0.f;
      f32x4 o0a = {0.f,0.f,0.f,0.f}, o0b = {0.f,0.f,0.f,0.f};
      f32x4 o1a = {0.f,0.f,0.f,0.f}, o1b = {0.f,0.f,0.f,0.f};
#pragma unroll
      for (int kt = 0; kt < 13; kt++) {
        s16x8 ka = *(const s16x8*)&k_s[(kt * 16 + col) * KS + quad * 8];   // one b128
        s16x4 ka0 = __builtin_shufflevector(ka, ka, 0, 1, 2, 3);
        s16x4 ka1 = __builtin_shufflevector(ka, ka, 4, 5, 6, 7);
        f32x4 acc = {0.f, 0.f, 0.f, 0.f};
        acc = MFMAX16(ka0, qb[i][0], acc);
        acc = MFMAX16(ka1, qb[i][1], acc);
        bf16x4 b4 = bl[kt];
        if (nxt) bl[kt] = *(const bf16x4*)(bpn + kt * 4);   // refill for next tile (WAR-safe)
        bf16x4 pk;
#pragma unroll
        for (int r = 0; r < 4; r++) {
          float e = __builtin_amdgcn_exp2f(acc[r] + (float)b4[r]);
          if (kt == 12 && quad != 0) e = 0.f;   // kj >= 196 masked
          sum += e;
          pk[r] = (__bf16)e;
        }
        s16x4 pv = __builtin_bit_cast(s16x4, pk);
        s16x4 va0 = *(const s16x4*)&vT_s[col * VS + kt * 16 + quad * 4];
        s16x4 va1 = *(const s16x4*)&vT_s[(16 + col) * VS + kt * 16 + quad * 4];
        if (kt & 1) { o0b = MFMAX16(va0, pv, o0b); o1b = MFMAX16(va1, pv, o1b); }
        else        { o0a = MFMAX16(va0, pv, o0a); o1a = MFMAX16(va1, pv, o1a); }
      }
      sum += __shfl_xor(sum, 16);
      sum += __shfl_xor(sum, 32);
      float inv = 1.f / sum;
      if (qi < 196) {
        __bf16* og = Og + ((size_t)b * 196 + qi) * 128 + h * 32;
        bf16x4 s0, s1;
#pragma unroll
        for (int r = 0; r < 4; r++) {
          s0[r] = (__bf16)((o0a[r] + o0b[r]) * inv);
          s1[r] = (__bf16)((o1a[r] + o1b[r]) * inv);
        }
        *(bf16x4*)&og[quad * 4]      = s0;
        *(bf16x4*)&og[16 + quad * 4] = s1;
      }
    }
  }
#undef WG
}

// ---------------- output projection: out = O @ wproj + bproj -----------------
// LDS-free, barrier-free: each wave owns one 16-row M-tile.
__launch_bounds__(256, 4)
__global__ void k_proj(const __bf16* __restrict__ Og, const __bf16* __restrict__ wpT,
                       const float* __restrict__ bproj, float* __restrict__ out) {
  int tid = threadIdx.x, wv = tid >> 6, lane = tid & 63, col = lane & 15, quad = lane >> 4;
  size_t rb = (size_t)blockIdx.x * 64 + wv * 16;   // wave's 16-row tile
  const __bf16* arow = Og + (rb + col) * 128 + quad * 8;
  bf16x8 af[4];
#pragma unroll
  for (int kc = 0; kc < 4; kc++) af[kc] = *(const bf16x8*)(arow + kc * 32);
#pragma unroll
  for (int nt = 0; nt < 8; nt++) {          // swapped: D[od][token]
    f32x4 acc = {0.f, 0.f, 0.f, 0.f};
#pragma unroll
    for (int kc = 0; kc < 4; kc++)
      acc = MFMA32(*(const bf16x8*)&wpT[(size_t)(nt * 16 + col) * 128 + kc * 32 + quad * 8],
                   af[kc], acc);
    int od = nt * 16 + quad * 4;
    float4 bp = *(const float4*)&bproj[od];
    float4 st = { acc[0] + bp.x, acc[1] + bp.y, acc[2] + bp.z, acc[3] + bp.w };
    *(float4*)&out[(rb + col) * 128 + od] = st;
  }
}

extern "C" void kernel_launch(void* const* d_in, const int* in_sizes, int n_in,
                              void* d_out, int out_size, void* d_ws, size_t ws_size,
                              hipStream_t stream) {
  const float* x     = (const float*)d_in[0];
  const float* wq    = (const float*)d_in[1];
  const float* wkv   = (const float*)d_in[2];
  const float* wproj = (const float*)d_in[3];
  const float* bproj = (const float*)d_in[4];
  const float* pp_w  = (const float*)d_in[5];
  const float* pp_b  = (const float*)d_in[6];
  const float* ln1_g = (const float*)d_in[7];
  const float* ln1_b = (const float*)d_in[8];
  const float* l1_w  = (const float*)d_in[9];
  const float* l1_b  = (const float*)d_in[10];
  const float* ln2_g = (const float*)d_in[11];
  const float* ln2_b = (const float*)d_in[12];
  const float* l2_w  = (const float*)d_in[13];
  const float* l2_b  = (const float*)d_in[14];
  const float* ln3_g = (const float*)d_in[15];
  const float* ln3_b = (const float*)d_in[16];
  const float* l3_w  = (const float*)d_in[17];
  const float* l3_b  = (const float*)d_in[18];
  float* out = (float*)d_out;

  char* ws = (char*)d_ws;
  __bf16* wF    = (__bf16*)ws;                  //  98304 B  [4][3][2][4][64][8]
  __bf16* wpT   = (__bf16*)(ws + 98304);        //  32768 B  [128][128]
  __bf16* biasP = (__bf16*)(ws + 131072);       // 346112 B  [4][208][4][52]
  __bf16* Og    = (__bf16*)(ws + 477184);       // 51380224 B [B][196][128]

  k_prep<<<257, 256, 0, stream>>>(wq, wkv, wproj, pp_w, pp_b,
                                  ln1_g, ln1_b, l1_w, l1_b,
                                  ln2_g, ln2_b, l2_w, l2_b,
                                  ln3_g, ln3_b, l3_w, l3_b,
                                  wF, wpT, biasP);
  k_attn<<<4096, 256, 0, stream>>>(x, wF, biasP, Og);
  k_proj<<<3136, 256, 0, stream>>>(Og, wpT, bproj, out);
}

// Round 2
// 365.200 us; speedup vs baseline: 1.1377x; 1.1377x over previous
//
#include <hip/hip_runtime.h>

typedef __attribute__((ext_vector_type(8))) __bf16 bf16x8;
typedef __attribute__((ext_vector_type(4))) __bf16 bf16x4;
typedef __attribute__((ext_vector_type(4))) float f32x4;
typedef __attribute__((ext_vector_type(4))) short s16x4;

#define MFMA32(a,b,c) __builtin_amdgcn_mfma_f32_16x16x32_bf16(a, b, c, 0, 0, 0)

static __device__ inline f32x4 MFMAX16(s16x4 a, s16x4 b, f32x4 c) {
#if __has_builtin(__builtin_amdgcn_mfma_f32_16x16x16bf16_1k)
  return __builtin_amdgcn_mfma_f32_16x16x16bf16_1k(a, b, c, 0, 0, 0);
#else
  f32x4 d;
  asm("v_mfma_f32_16x16x16_bf16 %0, %1, %2, %3" : "=v"(d) : "v"(a), "v"(b), "v"(c));
  return d;
#endif
}

#define KS 36    // k_s row stride (elems) — stride 72B: col*18%32 covers 16 banks, conflict-free
#define VS 212   // vT_s row stride (elems)
#define NW 4     // waves per block
#define LOG2E 1.4426950408889634f

__device__ inline bf16x8 load_a_f32(const float* p) {
  const float4* q = (const float4*)p;
  float4 u = q[0], v = q[1];
  bf16x8 r;
  r[0] = (__bf16)u.x; r[1] = (__bf16)u.y; r[2] = (__bf16)u.z; r[3] = (__bf16)u.w;
  r[4] = (__bf16)v.x; r[5] = (__bf16)v.y; r[6] = (__bf16)v.z; r[7] = (__bf16)v.w;
  return r;
}

__device__ inline void lnrelu8(float* v, const float* g, const float* bta) {
  float mu = 0.f;
#pragma unroll
  for (int i = 0; i < 8; i++) mu += v[i];
  mu *= 0.125f;
  float var = 0.f;
#pragma unroll
  for (int i = 0; i < 8; i++) { float d = v[i] - mu; var += d * d; }
  var *= 0.125f;
  float inv = rsqrtf(var + 1e-5f);
#pragma unroll
  for (int i = 0; i < 8; i++) v[i] = fmaxf((v[i] - mu) * inv * g[i] + bta[i], 0.f);
}

// ---- merged prep: blocks 0..87 weight repack; blocks 88..256 pos-MLP + bias table
// biasP layout: [h][qi][quad][kt*4+r]  (52 elems = 104B contiguous per (qi,quad) lane-row,
// so k_attn loads its 13 kt chunks as dense dwordx2 with immediate offsets off ONE base).
// Values pre-multiplied by log2e so k_attn can use raw v_exp_f32 (exp2).
__global__ void k_prep(const float* __restrict__ wq, const float* __restrict__ wkv,
                       const float* __restrict__ wproj,
                       const float* __restrict__ pp_w, const float* __restrict__ pp_b,
                       const float* ln1_g, const float* ln1_b, const float* l1_w, const float* l1_b,
                       const float* ln2_g, const float* ln2_b, const float* l2_w, const float* l2_b,
                       const float* ln3_g, const float* ln3_b, const float* l3_w, const float* l3_b,
                       __bf16* __restrict__ wF, __bf16* __restrict__ wpT,
                       __bf16* __restrict__ biasP) {
  __shared__ float pos_s[4 * 729];
  int blk = blockIdx.x, tid = threadIdx.x;
  if (blk < 88) {
    int t = blk * 256 + tid;
    if (t < 6144) {          // 96 frags x 64 lanes; frag = ((h*3+tt)*2+nt)*4+kc
      int lane = t & 63, frag = t >> 6;
      int kc = frag & 3, nt = (frag >> 2) & 1, tt = (frag >> 3) % 3, h = frag / 24;
      int col = lane & 15, quad = lane >> 4;
      int o = h * 32 + nt * 16 + col;
      int ibase = kc * 32 + quad * 8;
      bf16x8 vv;
#pragma unroll
      for (int j = 0; j < 8; j++) {
        int in = ibase + j;
        float w = (tt == 0) ? wq[in * 128 + o]
                : (tt == 1) ? wkv[in * 256 + o]
                            : wkv[in * 256 + 128 + o];
        vv[j] = (__bf16)w;
      }
      *(bf16x8*)&wF[(size_t)t * 8] = vv;
    } else if (t < 6144 + 16384) {
      int t2 = t - 6144;
      int o = t2 >> 7, i = t2 & 127;
      wpT[t2] = (__bf16)wproj[i * 128 + o];
    }
    return;
  }
  // bias blocks: recompute the tiny pos MLP into LDS, then emit bias slice
  for (int m = tid; m < 729; m += 256) {
    float dr = (float)(m / 27) - 13.f, dc = (float)(m % 27) - 13.f;
    float a[8], bv[8];
#pragma unroll
    for (int j = 0; j < 8; j++) a[j] = dr * pp_w[j] + dc * pp_w[8 + j] + pp_b[j];
    lnrelu8(a, ln1_g, ln1_b);
#pragma unroll
    for (int o = 0; o < 8; o++) {
      float s = l1_b[o];
#pragma unroll
      for (int j = 0; j < 8; j++) s += a[j] * l1_w[j * 8 + o];
      bv[o] = s;
    }
    lnrelu8(bv, ln2_g, ln2_b);
#pragma unroll
    for (int o = 0; o < 8; o++) {
      float s = l2_b[o];
#pragma unroll
      for (int j = 0; j < 8; j++) s += bv[j] * l2_w[j * 8 + o];
      a[o] = s;
    }
    lnrelu8(a, ln3_g, ln3_b);
#pragma unroll
    for (int o = 0; o < 4; o++) {
      float s = l3_b[o];
#pragma unroll
      for (int j = 0; j < 8; j++) s += a[j] * l3_w[j * 4 + o];
      pos_s[o * 729 + m] = s;
    }
  }
  __syncthreads();
  int t = (blk - 88) * 256 + tid;           // 169*256 == 4*208*52 exactly
  int g = t % 52; int rem = t / 52; int qi = rem % 208; int h = rem / 208;
  int kt = g >> 2, qd = g & 3;              // kj = kt*16 + qd*4 + r
  int kj0 = g * 4;
  int r1 = qi / 14, c1 = qi % 14;
  bf16x4 o;
#pragma unroll
  for (int r = 0; r < 4; r++) {
    int kj = kj0 + r;
    float v = 0.f;
    if (qi < 196 && kj < 196) {
      int r2 = kj / 14, c2 = kj % 14;
      v = pos_s[h * 729 + (r1 - r2 + 13) * 27 + (c1 - c2 + 13)];
    }
    o[r] = (__bf16)(v * LOG2E);
  }
  *(bf16x4*)&biasP[(((size_t)h * 208 + qi) * 4 + qd) * 52 + kt * 4] = o;
}

// ---------------- fused attention: one block (4 waves) per (b,h) -------------
// Round-0 proven structure (split S / PV loops, pp[13] kept in regs).
// amdgpu_waves_per_eu(4,4): pins the scheduler's occupancy target to 4 waves/EU
// so the register budget is 128 VGPRs — bl[13]+pp[13]+qb stay live instead of
// the compiler sinking the bias loads onto the per-kt critical path (the 64-VGPR
// bucket behavior observed in rounds 0-1). LDS caps residency at 5 blocks/CU
// and measured occupancy was ~3.2, so the cap costs nothing.
__launch_bounds__(256)
__attribute__((amdgpu_waves_per_eu(4, 4)))
__global__ void k_attn(const float* __restrict__ x, const __bf16* __restrict__ wF,
                       const __bf16* __restrict__ biasP, __bf16* __restrict__ Og) {
  __shared__ __align__(16) __bf16 k_s[208 * KS];    // 14976 B [token][d]
  __shared__ __align__(16) __bf16 vT_s[32 * VS];    // 13568 B [d][token]

  int tid = threadIdx.x;
  int wv = tid >> 6, lane = tid & 63, col = lane & 15, quad = lane >> 4;
  int bi = blockIdx.x;
  int b = (bi & 7) * 128 + (bi >> 5);   // same-b heads -> same XCD
  int h = (bi >> 3) & 3;

  const __bf16* wH = wF + (size_t)h * 12288;
#define WG(t, nt, kc) (*(const bf16x8*)&wH[(((t) * 2 + (nt)) * 4 + (kc)) * 512 + lane * 8])

  const float* xb = x + (size_t)b * (196 * 128);
  const float scale = 0.17677669529663687f * LOG2E;   // 32^-0.5, exp2-folded

  s16x4 qb[4][2];   // persisted q B-frags for this wave's tiles

  // ---- Stage B: per owned tile, load x once; compute k,v -> LDS and q -> regs
#pragma unroll
  for (int i = 0; i < 4; i++) {
    int qt = wv + i * NW;
    if (qt < 13) {
      int row = qt * 16 + col;
      const float* ap = xb + (size_t)(row < 196 ? row : 0) * 128 + quad * 8;
      bf16x8 xf[4];
#pragma unroll
      for (int kc = 0; kc < 4; kc++) xf[kc] = load_a_f32(ap + kc * 32);
#pragma unroll
      for (int nt = 0; nt < 2; nt++) {       // k, swapped: D[od][token]
        f32x4 acc = {0.f, 0.f, 0.f, 0.f};
#pragma unroll
        for (int kc = 0; kc < 4; kc++) acc = MFMA32(WG(1, nt, kc), xf[kc], acc);
        bf16x4 pk;
#pragma unroll
        for (int r = 0; r < 4; r++) pk[r] = (__bf16)acc[r];
        *(bf16x4*)&k_s[row * KS + nt * 16 + quad * 4] = pk;
      }
#pragma unroll
      for (int nt = 0; nt < 2; nt++) {       // v, normal: D[token][od] -> vT_s[od][token]
        f32x4 acc = {0.f, 0.f, 0.f, 0.f};
#pragma unroll
        for (int kc = 0; kc < 4; kc++) acc = MFMA32(xf[kc], WG(2, nt, kc), acc);
        bf16x4 pk;
#pragma unroll
        for (int r = 0; r < 4; r++) pk[r] = (__bf16)acc[r];
        *(bf16x4*)&vT_s[(nt * 16 + col) * VS + qt * 16 + quad * 4] = pk;
      }
#pragma unroll
      for (int nt = 0; nt < 2; nt++) {       // q, swapped -> registers (scale exp2-folded)
        f32x4 acc = {0.f, 0.f, 0.f, 0.f};
#pragma unroll
        for (int kc = 0; kc < 4; kc++) acc = MFMA32(WG(0, nt, kc), xf[kc], acc);
        bf16x4 pk;
#pragma unroll
        for (int r = 0; r < 4; r++) pk[r] = (__bf16)(acc[r] * scale);
        qb[i][nt] = __builtin_bit_cast(s16x4, pk);
      }
    }
  }
  __syncthreads();

  // ---- q-phase: per owned tile, S^T -> exp2 -> PV, all register-resident
#pragma unroll
  for (int i = 0; i < 4; i++) {
    int qt = wv + i * NW;
    if (qt < 13) {
      int qi = qt * 16 + col;
      const __bf16* bp = biasP + (((size_t)h * 208 + qi) * 4 + quad) * 52;
      bf16x4 bl[13];
#pragma unroll
      for (int kt = 0; kt < 13; kt++) bl[kt] = *(const bf16x4*)(bp + kt * 4);

      float sum = 0.f;
      s16x4 pp[13];
#pragma unroll
      for (int kt = 0; kt < 13; kt++) {
        s16x4 ka0 = *(const s16x4*)&k_s[(kt * 16 + col) * KS + quad * 4];
        s16x4 ka1 = *(const s16x4*)&k_s[(kt * 16 + col) * KS + 16 + quad * 4];
        f32x4 acc = {0.f, 0.f, 0.f, 0.f};
        acc = MFMAX16(ka0, qb[i][0], acc);
        acc = MFMAX16(ka1, qb[i][1], acc);
        bf16x4 pk;
#pragma unroll
        for (int r = 0; r < 4; r++) {
          float e = __builtin_amdgcn_exp2f(acc[r] + (float)bl[kt][r]);
          if (kt == 12 && quad != 0) e = 0.f;   // kj >= 196 masked
          sum += e;
          pk[r] = (__bf16)e;
        }
        pp[kt] = __builtin_bit_cast(s16x4, pk);
      }
      sum += __shfl_xor(sum, 16);
      sum += __shfl_xor(sum, 32);
      float inv = 1.f / sum;

      // O^T = V^T P^T, split even/odd accumulator chains
      f32x4 o0a = {0.f,0.f,0.f,0.f}, o0b = {0.f,0.f,0.f,0.f};
      f32x4 o1a = {0.f,0.f,0.f,0.f}, o1b = {0.f,0.f,0.f,0.f};
#pragma unroll
      for (int kt = 0; kt < 13; kt++) {
        s16x4 va0 = *(const s16x4*)&vT_s[col * VS + kt * 16 + quad * 4];
        s16x4 va1 = *(const s16x4*)&vT_s[(16 + col) * VS + kt * 16 + quad * 4];
        if (kt & 1) { o0b = MFMAX16(va0, pp[kt], o0b); o1b = MFMAX16(va1, pp[kt], o1b); }
        else        { o0a = MFMAX16(va0, pp[kt], o0a); o1a = MFMAX16(va1, pp[kt], o1a); }
      }
      if (qi < 196) {
        __bf16* og = Og + ((size_t)b * 196 + qi) * 128 + h * 32;
        bf16x4 s0, s1;
#pragma unroll
        for (int r = 0; r < 4; r++) {
          s0[r] = (__bf16)((o0a[r] + o0b[r]) * inv);
          s1[r] = (__bf16)((o1a[r] + o1b[r]) * inv);
        }
        *(bf16x4*)&og[quad * 4]      = s0;
        *(bf16x4*)&og[16 + quad * 4] = s1;
      }
    }
  }
#undef WG
}

// ---------------- output projection: out = O @ wproj + bproj -----------------
// LDS-free, barrier-free. 2 row-tiles per wave: halves wpT L2 re-reads
// (411 MB -> 206 MB) and doubles MFMA work per weight fragment load.
__launch_bounds__(256, 4)
__global__ void k_proj(const __bf16* __restrict__ Og, const __bf16* __restrict__ wpT,
                       const float* __restrict__ bproj, float* __restrict__ out) {
  int tid = threadIdx.x, wv = tid >> 6, lane = tid & 63, col = lane & 15, quad = lane >> 4;
  size_t rb = (size_t)blockIdx.x * 128 + wv * 16;   // wave's first 16-row tile; +64 second
  const __bf16* arow0 = Og + (rb + col) * 128 + quad * 8;
  const __bf16* arow1 = arow0 + (size_t)64 * 128;
  bf16x8 af0[4], af1[4];
#pragma unroll
  for (int kc = 0; kc < 4; kc++) {
    af0[kc] = *(const bf16x8*)(arow0 + kc * 32);
    af1[kc] = *(const bf16x8*)(arow1 + kc * 32);
  }
#pragma unroll
  for (int nt = 0; nt < 8; nt++) {          // swapped: D[od][token]
    f32x4 acc0 = {0.f, 0.f, 0.f, 0.f}, acc1 = {0.f, 0.f, 0.f, 0.f};
#pragma unroll
    for (int kc = 0; kc < 4; kc++) {
      bf16x8 w = *(const bf16x8*)&wpT[(size_t)(nt * 16 + col) * 128 + kc * 32 + quad * 8];
      acc0 = MFMA32(w, af0[kc], acc0);
      acc1 = MFMA32(w, af1[kc], acc1);
    }
    int od = nt * 16 + quad * 4;
    float4 bp = *(const float4*)&bproj[od];
    float4 st0 = { acc0[0] + bp.x, acc0[1] + bp.y, acc0[2] + bp.z, acc0[3] + bp.w };
    float4 st1 = { acc1[0] + bp.x, acc1[1] + bp.y, acc1[2] + bp.z, acc1[3] + bp.w };
    *(float4*)&out[(rb + col) * 128 + od] = st0;
    *(float4*)&out[(rb + 64 + col) * 128 + od] = st1;
  }
}

extern "C" void kernel_launch(void* const* d_in, const int* in_sizes, int n_in,
                              void* d_out, int out_size, void* d_ws, size_t ws_size,
                              hipStream_t stream) {
  const float* x     = (const float*)d_in[0];
  const float* wq    = (const float*)d_in[1];
  const float* wkv   = (const float*)d_in[2];
  const float* wproj = (const float*)d_in[3];
  const float* bproj = (const float*)d_in[4];
  const float* pp_w  = (const float*)d_in[5];
  const float* pp_b  = (const float*)d_in[6];
  const float* ln1_g = (const float*)d_in[7];
  const float* ln1_b = (const float*)d_in[8];
  const float* l1_w  = (const float*)d_in[9];
  const float* l1_b  = (const float*)d_in[10];
  const float* ln2_g = (const float*)d_in[11];
  const float* ln2_b = (const float*)d_in[12];
  const float* l2_w  = (const float*)d_in[13];
  const float* l2_b  = (const float*)d_in[14];
  const float* ln3_g = (const float*)d_in[15];
  const float* ln3_b = (const float*)d_in[16];
  const float* l3_w  = (const float*)d_in[17];
  const float* l3_b  = (const float*)d_in[18];
  float* out = (float*)d_out;

  char* ws = (char*)d_ws;
  __bf16* wF    = (__bf16*)ws;                  //  98304 B  [4][3][2][4][64][8]
  __bf16* wpT   = (__bf16*)(ws + 98304);        //  32768 B  [128][128]
  __bf16* biasP = (__bf16*)(ws + 131072);       // 346112 B  [4][208][4][52]
  __bf16* Og    = (__bf16*)(ws + 477184);       // 51380224 B [B][196][128]

  k_prep<<<257, 256, 0, stream>>>(wq, wkv, wproj, pp_w, pp_b,
                                  ln1_g, ln1_b, l1_w, l1_b,
                                  ln2_g, ln2_b, l2_w, l2_b,
                                  ln3_g, ln3_b, l3_w, l3_b,
                                  wF, wpT, biasP);
  k_attn<<<4096, 256, 0, stream>>>(x, wF, biasP, Og);
  k_proj<<<1568, 256, 0, stream>>>(Og, wpT, bproj, out);
}